// Round 1
// baseline (2121.398 us; speedup 1.0000x reference)
//
#include <hip/hip_runtime.h>

// ---------------------------------------------------------------------------
// PiNet: 2x GCNConv + a2^T a2 readout + linear + softmax
// N=100000, E=3200000, D0=128, D1=D2=64, OUT=10
// All fp32. Scatter via atomicAdd (edges unsorted).
// Workspace layout (floats):
//   bufH : N*64   (h1, then h2)
//   bufA : N*64   (a1, then a2)
//   dinv : N      (deg -> rsqrt(deg))
//   h64  : 4096   (a2^T a2)
// ---------------------------------------------------------------------------

__global__ void fill_ones(float* __restrict__ p, int n) {
    int i = blockIdx.x * blockDim.x + threadIdx.x;
    if (i < n) p[i] = 1.0f;  // self-loop contributes 1 to deg
}

__global__ void deg_atomic(const int* __restrict__ dst, float* __restrict__ deg, int E) {
    int e = blockIdx.x * blockDim.x + threadIdx.x;
    if (e < E) atomicAdd(&deg[dst[e]], 1.0f);
}

__global__ void rsqrt_inplace(float* __restrict__ p, int n) {
    int i = blockIdx.x * blockDim.x + threadIdx.x;
    if (i < n) p[i] = rsqrtf(p[i]);
}

// H[n][j] = sum_k A[n][k] * W[k][j], j in [0,64). 16 nodes per 256-thread block.
template <int K>
__global__ void gemm_nk(const float* __restrict__ A, const float* __restrict__ W,
                        float* __restrict__ H, int N) {
    __shared__ float Ws[K * 64];
    __shared__ float xs[16 * K];
    const int tid  = threadIdx.x;
    const int base = blockIdx.x * 16;

    for (int idx = tid; idx < K * 64; idx += 256) Ws[idx] = W[idx];
    for (int idx = tid; idx < 16 * K; idx += 256) {
        int n = base + idx / K;
        xs[idx] = (n < N) ? A[(long long)n * K + (idx % K)] : 0.0f;
    }
    __syncthreads();

    const int col = tid & 63;
    const int nl  = tid >> 6;  // wave id 0..3
    float acc[4] = {0.f, 0.f, 0.f, 0.f};
    for (int k = 0; k < K; ++k) {
        float w = Ws[k * 64 + col];
#pragma unroll
        for (int i = 0; i < 4; ++i)
            acc[i] += xs[(nl * 4 + i) * K + k] * w;
    }
#pragma unroll
    for (int i = 0; i < 4; ++i) {
        int n = base + nl * 4 + i;
        if (n < N) H[(long long)n * 64 + col] = acc[i];
    }
}

// out[n][j] = b[j]  (accumulator init with bias)
__global__ void fill_bias(float* __restrict__ out, const float* __restrict__ b, long long total) {
    long long t = (long long)blockIdx.x * blockDim.x + threadIdx.x;
    if (t < total) out[t] = b[t & 63];
}

// edges: out[dst][j] += H[src][j] * dinv[src]*dinv[dst]
__global__ void agg_edges(const int* __restrict__ src, const int* __restrict__ dst,
                          const float* __restrict__ dinv, const float* __restrict__ H,
                          float* __restrict__ out, int E) {
    long long t = (long long)blockIdx.x * blockDim.x + threadIdx.x;
    int       j = (int)(t & 63);
    long long e = t >> 6;
    if (e < E) {
        int s = src[e], d = dst[e];
        float w = dinv[s] * dinv[d];
        atomicAdd(&out[(long long)d * 64 + j], H[(long long)s * 64 + j] * w);
    }
}

// self loops: out[n][j] += H[n][j] * dinv[n]^2
__global__ void agg_self(const float* __restrict__ dinv, const float* __restrict__ H,
                         float* __restrict__ out, int N) {
    long long t = (long long)blockIdx.x * blockDim.x + threadIdx.x;
    if (t < (long long)N * 64) {
        int n = (int)(t >> 6);
        float w = dinv[n] * dinv[n];
        atomicAdd(&out[t], H[t] * w);
    }
}

// h64[r][c] += sum_n A2[n][r] * A2[n][c]
__global__ void outer_reduce(const float* __restrict__ A2, float* __restrict__ h64, int N) {
    __shared__ float rows[8][64];
    const int tid = threadIdx.x;
    const int col = tid & 63;
    const int rg  = tid >> 6;  // row group: rows rg*16 .. rg*16+15
    float acc[16];
#pragma unroll
    for (int i = 0; i < 16; ++i) acc[i] = 0.f;

    int npb   = (N + gridDim.x - 1) / gridDim.x;
    int start = blockIdx.x * npb;
    int end   = min(start + npb, N);
    for (int nb = start; nb < end; nb += 8) {
        int cnt = min(8, end - nb);
        __syncthreads();
        for (int idx = tid; idx < cnt * 64; idx += 256)
            rows[idx >> 6][idx & 63] = A2[(long long)(nb + (idx >> 6)) * 64 + (idx & 63)];
        __syncthreads();
        for (int r = 0; r < cnt; ++r) {
            float vc = rows[r][col];
#pragma unroll
            for (int i = 0; i < 16; ++i)
                acc[i] += rows[r][rg * 16 + i] * vc;
        }
    }
#pragma unroll
    for (int i = 0; i < 16; ++i)
        atomicAdd(&h64[(rg * 16 + i) * 64 + col], acc[i]);
}

// o = h64.flat @ Wl + bl ; softmax -> out[10]
__global__ void final_kernel(const float* __restrict__ h64, const float* __restrict__ Wl,
                             const float* __restrict__ bl, float* __restrict__ out) {
    __shared__ float red[256];
    __shared__ float o[10];
    const int tid = threadIdx.x;
    float acc[10];
#pragma unroll
    for (int k = 0; k < 10; ++k) acc[k] = 0.f;
    for (int i = tid; i < 4096; i += 256) {
        float v = h64[i];
#pragma unroll
        for (int k = 0; k < 10; ++k) acc[k] += v * Wl[i * 10 + k];
    }
    for (int k = 0; k < 10; ++k) {
        red[tid] = acc[k];
        __syncthreads();
        for (int s = 128; s > 0; s >>= 1) {
            if (tid < s) red[tid] += red[tid + s];
            __syncthreads();
        }
        if (tid == 0) o[k] = red[0] + bl[k];
        __syncthreads();
    }
    if (tid == 0) {
        float m = o[0];
        for (int k = 1; k < 10; ++k) m = fmaxf(m, o[k]);
        float s = 0.f, e[10];
        for (int k = 0; k < 10; ++k) { e[k] = expf(o[k] - m); s += e[k]; }
        for (int k = 0; k < 10; ++k) out[k] = e[k] / s;
    }
}

extern "C" void kernel_launch(void* const* d_in, const int* in_sizes, int n_in,
                              void* d_out, int out_size, void* d_ws, size_t ws_size,
                              hipStream_t stream) {
    const float* x   = (const float*)d_in[0];
    const int*   ei  = (const int*)d_in[1];
    const float* Wa1 = (const float*)d_in[2];
    const float* ba1 = (const float*)d_in[3];
    const float* Wa2 = (const float*)d_in[4];
    const float* ba2 = (const float*)d_in[5];
    const float* Wl  = (const float*)d_in[6];
    const float* bl  = (const float*)d_in[7];
    float* out = (float*)d_out;

    const int N = in_sizes[0] / 128;
    const int E = in_sizes[1] / 2;
    const int* src = ei;
    const int* dst = ei + E;

    float* ws   = (float*)d_ws;
    float* bufH = ws;                        // N*64
    float* bufA = ws + (size_t)N * 64;       // N*64
    float* dinv = ws + (size_t)N * 128;      // N
    float* h64  = dinv + N;                  // 4096

    const long long tot  = (long long)N * 64;
    const long long etot = (long long)E * 64;
    const int gTot  = (int)((tot + 255) / 256);
    const int gEtot = (int)((etot + 255) / 256);

    // degrees -> dinv
    fill_ones<<<(N + 255) / 256, 256, 0, stream>>>(dinv, N);
    deg_atomic<<<(E + 255) / 256, 256, 0, stream>>>(dst, dinv, E);
    rsqrt_inplace<<<(N + 255) / 256, 256, 0, stream>>>(dinv, N);

    // layer 1: h1 = x @ Wa1 ; a1 = scatter(norm * h1[src]) + ba1
    gemm_nk<128><<<(N + 15) / 16, 256, 0, stream>>>(x, Wa1, bufH, N);
    fill_bias<<<gTot, 256, 0, stream>>>(bufA, ba1, tot);
    agg_edges<<<gEtot, 256, 0, stream>>>(src, dst, dinv, bufH, bufA, E);
    agg_self<<<gTot, 256, 0, stream>>>(dinv, bufH, bufA, N);

    // layer 2: h2 = a1 @ Wa2 ; a2 = scatter(norm * h2[src]) + ba2
    gemm_nk<64><<<(N + 15) / 16, 256, 0, stream>>>(bufA, Wa2, bufH, N);
    fill_bias<<<gTot, 256, 0, stream>>>(bufA, ba2, tot);
    agg_edges<<<gEtot, 256, 0, stream>>>(src, dst, dinv, bufH, bufA, E);
    agg_self<<<gTot, 256, 0, stream>>>(dinv, bufH, bufA, N);

    // readout: h64 = a2^T a2 ; out = softmax(h64.flat @ Wl + bl)
    hipMemsetAsync(h64, 0, 4096 * sizeof(float), stream);
    outer_reduce<<<512, 256, 0, stream>>>(bufA, h64, N);
    final_kernel<<<1, 256, 0, stream>>>(h64, Wl, bl, out);
}

// Round 2
// 1148.208 us; speedup vs baseline: 1.8476x; 1.8476x over previous
//
#include <hip/hip_runtime.h>

// ---------------------------------------------------------------------------
// PiNet: 2x GCNConv + a2^T a2 readout + linear + softmax
// N=100000, E=3200000, D0=128, D1=D2=64, OUT=10
// R1: CSR-gather aggregation (no fp32 atomics), fused bias+self-loop.
// Workspace layout:
//   bufH   : N*64 f   (h1, then h2)
//   bufA   : N*64 f   (a1, then a2)
//   dinv   : N f
//   h64    : 4096 f
//   counts : N i      (in-degree histogram)
//   rowptr : N i      (exclusive prefix of counts)
//   cursor : N i      (scatter cursors; post-scatter = row end)
//   bsums  : 1024 i
//   ssorted: E i      (edge sources bucketed by dst)
// ---------------------------------------------------------------------------

#define SCAN_B 1024

__global__ void hist_dst(const int* __restrict__ dst, int* __restrict__ counts, int E) {
    int e = blockIdx.x * blockDim.x + threadIdx.x;
    if (e < E) atomicAdd(&counts[dst[e]], 1);
}

__global__ void dinv_from_counts(const int* __restrict__ counts, float* __restrict__ dinv, int N) {
    int i = blockIdx.x * blockDim.x + threadIdx.x;
    if (i < N) dinv[i] = rsqrtf((float)counts[i] + 1.0f);  // +1 self-loop
}

// exclusive scan, level A: per-block scan of counts -> rowptr, block totals -> bsums
__global__ void scanA(const int* __restrict__ counts, int* __restrict__ rowptr,
                      int* __restrict__ bsums, int N) {
    __shared__ int sh[SCAN_B];
    const int tid = threadIdx.x;
    const int i   = blockIdx.x * SCAN_B + tid;
    int c = (i < N) ? counts[i] : 0;
    sh[tid] = c;
    __syncthreads();
    for (int off = 1; off < SCAN_B; off <<= 1) {
        int t = (tid >= off) ? sh[tid - off] : 0;
        __syncthreads();
        sh[tid] += t;
        __syncthreads();
    }
    if (i < N) rowptr[i] = sh[tid] - c;  // exclusive
    if (tid == SCAN_B - 1) bsums[blockIdx.x] = sh[tid];
}

// level B: exclusive scan of block sums (nb <= 1024), single block
__global__ void scanB(int* __restrict__ bsums, int nb) {
    __shared__ int sh[SCAN_B];
    const int tid = threadIdx.x;
    if (tid < nb) sh[tid] = bsums[tid];
    __syncthreads();
    if (tid == 0) {
        int run = 0;
        for (int k = 0; k < nb; ++k) { int v = sh[k]; sh[k] = run; run += v; }
    }
    __syncthreads();
    if (tid < nb) bsums[tid] = sh[tid];
}

// level C: add block offsets; init cursor = rowptr
__global__ void scanC(int* __restrict__ rowptr, const int* __restrict__ bsums,
                      int* __restrict__ cursor, int N) {
    int i = blockIdx.x * blockDim.x + threadIdx.x;
    if (i < N) {
        int rp = rowptr[i] + bsums[i >> 10];
        rowptr[i] = rp;
        cursor[i] = rp;
    }
}

__global__ void scatter_edges(const int* __restrict__ src, const int* __restrict__ dst,
                              int* __restrict__ cursor, int* __restrict__ ssorted, int E) {
    int e = blockIdx.x * blockDim.x + threadIdx.x;
    if (e < E) {
        int pos = atomicAdd(&cursor[dst[e]], 1);
        ssorted[pos] = src[e];
    }
}

// H[n][j] = sum_k A[n][k] * W[k][j], j in [0,64). 16 nodes per 256-thread block.
template <int K>
__global__ void gemm_nk(const float* __restrict__ A, const float* __restrict__ W,
                        float* __restrict__ H, int N) {
    __shared__ float Ws[K * 64];
    __shared__ float xs[16 * K];
    const int tid  = threadIdx.x;
    const int base = blockIdx.x * 16;

    for (int idx = tid; idx < K * 64; idx += 256) Ws[idx] = W[idx];
    for (int idx = tid; idx < 16 * K; idx += 256) {
        int n = base + idx / K;
        xs[idx] = (n < N) ? A[(long long)n * K + (idx % K)] : 0.0f;
    }
    __syncthreads();

    const int col = tid & 63;
    const int nl  = tid >> 6;
    float acc[4] = {0.f, 0.f, 0.f, 0.f};
    for (int k = 0; k < K; ++k) {
        float w = Ws[k * 64 + col];
#pragma unroll
        for (int i = 0; i < 4; ++i)
            acc[i] += xs[(nl * 4 + i) * K + k] * w;
    }
#pragma unroll
    for (int i = 0; i < 4; ++i) {
        int n = base + nl * 4 + i;
        if (n < N) H[(long long)n * 64 + col] = acc[i];
    }
}

// CSR aggregation, fused bias + self-loop.
// One wave per node. 16 lanes per edge (float4 features), 4 edges in flight.
// out[n][:] = b + dinv[n]^2*H[n][:] + sum_e dinv[s_e]*dinv[n]*H[s_e][:]
__global__ void agg_csr(const int* __restrict__ rowptr, const int* __restrict__ endptr,
                        const int* __restrict__ ssorted, const float* __restrict__ dinv,
                        const float* __restrict__ H, const float* __restrict__ bias,
                        float* __restrict__ out, int N) {
    const int wid  = (int)(((long long)blockIdx.x * blockDim.x + threadIdx.x) >> 6);
    if (wid >= N) return;
    const int lane = threadIdx.x & 63;
    const int g    = lane >> 4;   // edge slot 0..3
    const int fl   = lane & 15;   // float4 feature group
    const float4* __restrict__ Hv = (const float4*)H;

    const int   n   = wid;
    const float dn  = dinv[n];
    const int   beg = rowptr[n];
    const int   end = endptr[n];

    float4 acc = make_float4(0.f, 0.f, 0.f, 0.f);
    for (int e = beg + g; e < end; e += 4) {
        int    s  = ssorted[e];
        float  w  = dinv[s] * dn;
        float4 hv = Hv[(long long)s * 16 + fl];
        acc.x += w * hv.x; acc.y += w * hv.y; acc.z += w * hv.z; acc.w += w * hv.w;
    }
    // reduce the 4 edge-groups (lanes differing in bits 4,5)
    acc.x += __shfl_xor(acc.x, 16); acc.y += __shfl_xor(acc.y, 16);
    acc.z += __shfl_xor(acc.z, 16); acc.w += __shfl_xor(acc.w, 16);
    acc.x += __shfl_xor(acc.x, 32); acc.y += __shfl_xor(acc.y, 32);
    acc.z += __shfl_xor(acc.z, 32); acc.w += __shfl_xor(acc.w, 32);

    if (g == 0) {
        float4 selfv = Hv[(long long)n * 16 + fl];
        float4 bv    = ((const float4*)bias)[fl];
        float  w0    = dn * dn;
        float4 res;
        res.x = bv.x + w0 * selfv.x + acc.x;
        res.y = bv.y + w0 * selfv.y + acc.y;
        res.z = bv.z + w0 * selfv.z + acc.z;
        res.w = bv.w + w0 * selfv.w + acc.w;
        ((float4*)out)[(long long)n * 16 + fl] = res;
    }
}

// h64[r][c] += sum_n A2[n][r] * A2[n][c]
__global__ void outer_reduce(const float* __restrict__ A2, float* __restrict__ h64, int N) {
    __shared__ float rows[8][64];
    const int tid = threadIdx.x;
    const int col = tid & 63;
    const int rg  = tid >> 6;
    float acc[16];
#pragma unroll
    for (int i = 0; i < 16; ++i) acc[i] = 0.f;

    int npb   = (N + gridDim.x - 1) / gridDim.x;
    int start = blockIdx.x * npb;
    int end   = min(start + npb, N);
    for (int nb = start; nb < end; nb += 8) {
        int cnt = min(8, end - nb);
        __syncthreads();
        for (int idx = tid; idx < cnt * 64; idx += 256)
            rows[idx >> 6][idx & 63] = A2[(long long)(nb + (idx >> 6)) * 64 + (idx & 63)];
        __syncthreads();
        for (int r = 0; r < cnt; ++r) {
            float vc = rows[r][col];
#pragma unroll
            for (int i = 0; i < 16; ++i)
                acc[i] += rows[r][rg * 16 + i] * vc;
        }
    }
#pragma unroll
    for (int i = 0; i < 16; ++i)
        atomicAdd(&h64[(rg * 16 + i) * 64 + col], acc[i]);
}

// o = h64.flat @ Wl + bl ; softmax -> out[10]
__global__ void final_kernel(const float* __restrict__ h64, const float* __restrict__ Wl,
                             const float* __restrict__ bl, float* __restrict__ out) {
    __shared__ float red[256];
    __shared__ float o[10];
    const int tid = threadIdx.x;
    float acc[10];
#pragma unroll
    for (int k = 0; k < 10; ++k) acc[k] = 0.f;
    for (int i = tid; i < 4096; i += 256) {
        float v = h64[i];
#pragma unroll
        for (int k = 0; k < 10; ++k) acc[k] += v * Wl[i * 10 + k];
    }
    for (int k = 0; k < 10; ++k) {
        red[tid] = acc[k];
        __syncthreads();
        for (int s = 128; s > 0; s >>= 1) {
            if (tid < s) red[tid] += red[tid + s];
            __syncthreads();
        }
        if (tid == 0) o[k] = red[0] + bl[k];
        __syncthreads();
    }
    if (tid == 0) {
        float m = o[0];
        for (int k = 1; k < 10; ++k) m = fmaxf(m, o[k]);
        float s = 0.f, e[10];
        for (int k = 0; k < 10; ++k) { e[k] = expf(o[k] - m); s += e[k]; }
        for (int k = 0; k < 10; ++k) out[k] = e[k] / s;
    }
}

extern "C" void kernel_launch(void* const* d_in, const int* in_sizes, int n_in,
                              void* d_out, int out_size, void* d_ws, size_t ws_size,
                              hipStream_t stream) {
    const float* x   = (const float*)d_in[0];
    const int*   ei  = (const int*)d_in[1];
    const float* Wa1 = (const float*)d_in[2];
    const float* ba1 = (const float*)d_in[3];
    const float* Wa2 = (const float*)d_in[4];
    const float* ba2 = (const float*)d_in[5];
    const float* Wl  = (const float*)d_in[6];
    const float* bl  = (const float*)d_in[7];
    float* out = (float*)d_out;

    const int N = in_sizes[0] / 128;
    const int E = in_sizes[1] / 2;
    const int* src = ei;
    const int* dst = ei + E;

    char* wsb = (char*)d_ws;
    float* bufH   = (float*)wsb;                       wsb += (size_t)N * 64 * 4;
    float* bufA   = (float*)wsb;                       wsb += (size_t)N * 64 * 4;
    float* dinv   = (float*)wsb;                       wsb += (size_t)N * 4;
    float* h64    = (float*)wsb;                       wsb += 4096 * 4;
    int*   counts = (int*)wsb;                         wsb += (size_t)N * 4;
    int*   rowptr = (int*)wsb;                         wsb += (size_t)N * 4;
    int*   cursor = (int*)wsb;                         wsb += (size_t)N * 4;
    int*   bsums  = (int*)wsb;                         wsb += 1024 * 4;
    int*   ssorted= (int*)wsb;                         wsb += (size_t)E * 4;

    const int gN = (N + 255) / 256;
    const int gE = (E + 255) / 256;
    const int nb = (N + SCAN_B - 1) / SCAN_B;

    // --- CSR build ---
    hipMemsetAsync(counts, 0, (size_t)N * 4, stream);
    hist_dst<<<gE, 256, 0, stream>>>(dst, counts, E);
    dinv_from_counts<<<gN, 256, 0, stream>>>(counts, dinv, N);
    scanA<<<nb, SCAN_B, 0, stream>>>(counts, rowptr, bsums, N);
    scanB<<<1, SCAN_B, 0, stream>>>(bsums, nb);
    scanC<<<gN, 256, 0, stream>>>(rowptr, bsums, cursor, N);
    scatter_edges<<<gE, 256, 0, stream>>>(src, dst, cursor, ssorted, E);

    // --- layer 1 ---
    gemm_nk<128><<<(N + 15) / 16, 256, 0, stream>>>(x, Wa1, bufH, N);
    agg_csr<<<(N + 3) / 4, 256, 0, stream>>>(rowptr, cursor, ssorted, dinv, bufH, ba1, bufA, N);

    // --- layer 2 ---
    gemm_nk<64><<<(N + 15) / 16, 256, 0, stream>>>(bufA, Wa2, bufH, N);
    agg_csr<<<(N + 3) / 4, 256, 0, stream>>>(rowptr, cursor, ssorted, dinv, bufH, ba2, bufA, N);

    // --- readout ---
    hipMemsetAsync(h64, 0, 4096 * sizeof(float), stream);
    outer_reduce<<<512, 256, 0, stream>>>(bufA, h64, N);
    final_kernel<<<1, 256, 0, stream>>>(h64, Wl, bl, out);
}

// Round 3
// 848.078 us; speedup vs baseline: 2.5014x; 1.3539x over previous
//
#include <hip/hip_runtime.h>

// ---------------------------------------------------------------------------
// PiNet: 2x GCNConv + a2^T a2 readout + linear + softmax
// N=100000, E=3200000, D0=128, D1=D2=64, OUT=10
// R2: register-tiled fp32 GEMM (4x4 per thread, float4 LDS reads);
//     CSR-gather aggregation kept from R1.
// ---------------------------------------------------------------------------

#define SCAN_B 1024

__global__ void hist_dst(const int* __restrict__ dst, int* __restrict__ counts, int E) {
    int e = blockIdx.x * blockDim.x + threadIdx.x;
    if (e < E) atomicAdd(&counts[dst[e]], 1);
}

__global__ void dinv_from_counts(const int* __restrict__ counts, float* __restrict__ dinv, int N) {
    int i = blockIdx.x * blockDim.x + threadIdx.x;
    if (i < N) dinv[i] = rsqrtf((float)counts[i] + 1.0f);  // +1 self-loop
}

// exclusive scan, level A: per-block scan of counts -> rowptr, block totals -> bsums
__global__ void scanA(const int* __restrict__ counts, int* __restrict__ rowptr,
                      int* __restrict__ bsums, int N) {
    __shared__ int sh[SCAN_B];
    const int tid = threadIdx.x;
    const int i   = blockIdx.x * SCAN_B + tid;
    int c = (i < N) ? counts[i] : 0;
    sh[tid] = c;
    __syncthreads();
    for (int off = 1; off < SCAN_B; off <<= 1) {
        int t = (tid >= off) ? sh[tid - off] : 0;
        __syncthreads();
        sh[tid] += t;
        __syncthreads();
    }
    if (i < N) rowptr[i] = sh[tid] - c;  // exclusive
    if (tid == SCAN_B - 1) bsums[blockIdx.x] = sh[tid];
}

// level B: exclusive scan of block sums (nb <= 1024), single block
__global__ void scanB(int* __restrict__ bsums, int nb) {
    __shared__ int sh[SCAN_B];
    const int tid = threadIdx.x;
    if (tid < nb) sh[tid] = bsums[tid];
    __syncthreads();
    if (tid == 0) {
        int run = 0;
        for (int k = 0; k < nb; ++k) { int v = sh[k]; sh[k] = run; run += v; }
    }
    __syncthreads();
    if (tid < nb) bsums[tid] = sh[tid];
}

// level C: add block offsets; init cursor = rowptr
__global__ void scanC(int* __restrict__ rowptr, const int* __restrict__ bsums,
                      int* __restrict__ cursor, int N) {
    int i = blockIdx.x * blockDim.x + threadIdx.x;
    if (i < N) {
        int rp = rowptr[i] + bsums[i >> 10];
        rowptr[i] = rp;
        cursor[i] = rp;
    }
}

__global__ void scatter_edges(const int* __restrict__ src, const int* __restrict__ dst,
                              int* __restrict__ cursor, int* __restrict__ ssorted, int E) {
    int e = blockIdx.x * blockDim.x + threadIdx.x;
    if (e < E) {
        int pos = atomicAdd(&cursor[dst[e]], 1);
        ssorted[pos] = src[e];
    }
}

// ---------------------------------------------------------------------------
// Register-tiled GEMM: H[n][c] = sum_k A[n][k]*W[k][c], c in [0,64).
// 64 nodes x 64 cols per 256-thread block; each thread computes 4 nodes x 4 cols.
// K staged in LDS chunks of 32; all LDS traffic is ds_read_b128.
// ---------------------------------------------------------------------------
template <int K>
__global__ __launch_bounds__(256) void gemm_tiled(const float* __restrict__ A,
                                                  const float* __restrict__ W,
                                                  float* __restrict__ H, int N) {
    constexpr int KC = 32;
    __shared__ float xs[64][KC + 4];  // stride 36 floats = 144 B (16B-aligned, 2-way banks)
    __shared__ float ws[KC][64];
    const int tid  = threadIdx.x;
    const int tx   = tid & 15;   // col group  (cols tx*4 .. tx*4+3)
    const int ty   = tid >> 4;   // node group (nodes ty*4 .. ty*4+3)
    const int base = blockIdx.x * 64;

    float acc[4][4] = {{0.f}};

    for (int kc = 0; kc < K; kc += KC) {
        // stage xs: 64 nodes x 32 k = 512 float4s
        for (int idx = tid; idx < 512; idx += 256) {
            int node = idx >> 3, k4 = idx & 7;
            int n = base + node;
            float4 v = make_float4(0.f, 0.f, 0.f, 0.f);
            if (n < N) v = *(const float4*)&A[(long long)n * K + kc + k4 * 4];
            *(float4*)&xs[node][k4 * 4] = v;
        }
        // stage ws: 32 k x 64 cols = 512 float4s
        for (int idx = tid; idx < 512; idx += 256) {
            int k = idx >> 4, c4 = idx & 15;
            *(float4*)&ws[k][c4 * 4] = *(const float4*)&W[(long long)(kc + k) * 64 + c4 * 4];
        }
        __syncthreads();

#pragma unroll
        for (int k = 0; k < KC; k += 4) {
            float4 xv[4], wv[4];
#pragma unroll
            for (int i = 0; i < 4; ++i) xv[i] = *(const float4*)&xs[ty * 4 + i][k];
#pragma unroll
            for (int j = 0; j < 4; ++j) wv[j] = *(const float4*)&ws[k + j][tx * 4];
#pragma unroll
            for (int i = 0; i < 4; ++i) {
                float xi[4] = {xv[i].x, xv[i].y, xv[i].z, xv[i].w};
#pragma unroll
                for (int j = 0; j < 4; ++j) {
                    acc[i][0] += xi[j] * wv[j].x;
                    acc[i][1] += xi[j] * wv[j].y;
                    acc[i][2] += xi[j] * wv[j].z;
                    acc[i][3] += xi[j] * wv[j].w;
                }
            }
        }
        __syncthreads();
    }

#pragma unroll
    for (int i = 0; i < 4; ++i) {
        int n = base + ty * 4 + i;
        if (n < N) {
            float4 r = make_float4(acc[i][0], acc[i][1], acc[i][2], acc[i][3]);
            *(float4*)&H[(long long)n * 64 + tx * 4] = r;
        }
    }
}

// CSR aggregation, fused bias + self-loop.
// One wave per node. 16 lanes per edge (float4 features), 4 edges in flight.
__global__ void agg_csr(const int* __restrict__ rowptr, const int* __restrict__ endptr,
                        const int* __restrict__ ssorted, const float* __restrict__ dinv,
                        const float* __restrict__ H, const float* __restrict__ bias,
                        float* __restrict__ out, int N) {
    const int wid  = (int)(((long long)blockIdx.x * blockDim.x + threadIdx.x) >> 6);
    if (wid >= N) return;
    const int lane = threadIdx.x & 63;
    const int g    = lane >> 4;   // edge slot 0..3
    const int fl   = lane & 15;   // float4 feature group
    const float4* __restrict__ Hv = (const float4*)H;

    const int   n   = wid;
    const float dn  = dinv[n];
    const int   beg = rowptr[n];
    const int   end = endptr[n];

    float4 acc = make_float4(0.f, 0.f, 0.f, 0.f);
    for (int e = beg + g; e < end; e += 4) {
        int    s  = ssorted[e];
        float  w  = dinv[s] * dn;
        float4 hv = Hv[(long long)s * 16 + fl];
        acc.x += w * hv.x; acc.y += w * hv.y; acc.z += w * hv.z; acc.w += w * hv.w;
    }
    acc.x += __shfl_xor(acc.x, 16); acc.y += __shfl_xor(acc.y, 16);
    acc.z += __shfl_xor(acc.z, 16); acc.w += __shfl_xor(acc.w, 16);
    acc.x += __shfl_xor(acc.x, 32); acc.y += __shfl_xor(acc.y, 32);
    acc.z += __shfl_xor(acc.z, 32); acc.w += __shfl_xor(acc.w, 32);

    if (g == 0) {
        float4 selfv = Hv[(long long)n * 16 + fl];
        float4 bv    = ((const float4*)bias)[fl];
        float  w0    = dn * dn;
        float4 res;
        res.x = bv.x + w0 * selfv.x + acc.x;
        res.y = bv.y + w0 * selfv.y + acc.y;
        res.z = bv.z + w0 * selfv.z + acc.z;
        res.w = bv.w + w0 * selfv.w + acc.w;
        ((float4*)out)[(long long)n * 16 + fl] = res;
    }
}

// h64[r][c] += sum_n A2[n][r] * A2[n][c]
__global__ void outer_reduce(const float* __restrict__ A2, float* __restrict__ h64, int N) {
    __shared__ float rows[8][64];
    const int tid = threadIdx.x;
    const int col = tid & 63;
    const int rg  = tid >> 6;
    float acc[16];
#pragma unroll
    for (int i = 0; i < 16; ++i) acc[i] = 0.f;

    int npb   = (N + gridDim.x - 1) / gridDim.x;
    int start = blockIdx.x * npb;
    int end   = min(start + npb, N);
    for (int nb = start; nb < end; nb += 8) {
        int cnt = min(8, end - nb);
        __syncthreads();
        for (int idx = tid; idx < cnt * 64; idx += 256)
            rows[idx >> 6][idx & 63] = A2[(long long)(nb + (idx >> 6)) * 64 + (idx & 63)];
        __syncthreads();
        for (int r = 0; r < cnt; ++r) {
            float vc = rows[r][col];
#pragma unroll
            for (int i = 0; i < 16; ++i)
                acc[i] += rows[r][rg * 16 + i] * vc;
        }
    }
#pragma unroll
    for (int i = 0; i < 16; ++i)
        atomicAdd(&h64[(rg * 16 + i) * 64 + col], acc[i]);
}

// o = h64.flat @ Wl + bl ; softmax -> out[10]
__global__ void final_kernel(const float* __restrict__ h64, const float* __restrict__ Wl,
                             const float* __restrict__ bl, float* __restrict__ out) {
    __shared__ float red[256];
    __shared__ float o[10];
    const int tid = threadIdx.x;
    float acc[10];
#pragma unroll
    for (int k = 0; k < 10; ++k) acc[k] = 0.f;
    for (int i = tid; i < 4096; i += 256) {
        float v = h64[i];
#pragma unroll
        for (int k = 0; k < 10; ++k) acc[k] += v * Wl[i * 10 + k];
    }
    for (int k = 0; k < 10; ++k) {
        red[tid] = acc[k];
        __syncthreads();
        for (int s = 128; s > 0; s >>= 1) {
            if (tid < s) red[tid] += red[tid + s];
            __syncthreads();
        }
        if (tid == 0) o[k] = red[0] + bl[k];
        __syncthreads();
    }
    if (tid == 0) {
        float m = o[0];
        for (int k = 1; k < 10; ++k) m = fmaxf(m, o[k]);
        float s = 0.f, e[10];
        for (int k = 0; k < 10; ++k) { e[k] = expf(o[k] - m); s += e[k]; }
        for (int k = 0; k < 10; ++k) out[k] = e[k] / s;
    }
}

extern "C" void kernel_launch(void* const* d_in, const int* in_sizes, int n_in,
                              void* d_out, int out_size, void* d_ws, size_t ws_size,
                              hipStream_t stream) {
    const float* x   = (const float*)d_in[0];
    const int*   ei  = (const int*)d_in[1];
    const float* Wa1 = (const float*)d_in[2];
    const float* ba1 = (const float*)d_in[3];
    const float* Wa2 = (const float*)d_in[4];
    const float* ba2 = (const float*)d_in[5];
    const float* Wl  = (const float*)d_in[6];
    const float* bl  = (const float*)d_in[7];
    float* out = (float*)d_out;

    const int N = in_sizes[0] / 128;
    const int E = in_sizes[1] / 2;
    const int* src = ei;
    const int* dst = ei + E;

    char* wsb = (char*)d_ws;
    float* bufH   = (float*)wsb;                       wsb += (size_t)N * 64 * 4;
    float* bufA   = (float*)wsb;                       wsb += (size_t)N * 64 * 4;
    float* dinv   = (float*)wsb;                       wsb += (size_t)N * 4;
    float* h64    = (float*)wsb;                       wsb += 4096 * 4;
    int*   counts = (int*)wsb;                         wsb += (size_t)N * 4;
    int*   rowptr = (int*)wsb;                         wsb += (size_t)N * 4;
    int*   cursor = (int*)wsb;                         wsb += (size_t)N * 4;
    int*   bsums  = (int*)wsb;                         wsb += 1024 * 4;
    int*   ssorted= (int*)wsb;                         wsb += (size_t)E * 4;

    const int gN = (N + 255) / 256;
    const int gE = (E + 255) / 256;
    const int nb = (N + SCAN_B - 1) / SCAN_B;

    // --- CSR build ---
    hipMemsetAsync(counts, 0, (size_t)N * 4, stream);
    hist_dst<<<gE, 256, 0, stream>>>(dst, counts, E);
    dinv_from_counts<<<gN, 256, 0, stream>>>(counts, dinv, N);
    scanA<<<nb, SCAN_B, 0, stream>>>(counts, rowptr, bsums, N);
    scanB<<<1, SCAN_B, 0, stream>>>(bsums, nb);
    scanC<<<gN, 256, 0, stream>>>(rowptr, bsums, cursor, N);
    scatter_edges<<<gE, 256, 0, stream>>>(src, dst, cursor, ssorted, E);

    // --- layer 1 ---
    gemm_tiled<128><<<(N + 63) / 64, 256, 0, stream>>>(x, Wa1, bufH, N);
    agg_csr<<<(N + 3) / 4, 256, 0, stream>>>(rowptr, cursor, ssorted, dinv, bufH, ba1, bufA, N);

    // --- layer 2 ---
    gemm_tiled<64><<<(N + 63) / 64, 256, 0, stream>>>(bufA, Wa2, bufH, N);
    agg_csr<<<(N + 3) / 4, 256, 0, stream>>>(rowptr, cursor, ssorted, dinv, bufH, ba2, bufA, N);

    // --- readout ---
    hipMemsetAsync(h64, 0, 4096 * sizeof(float), stream);
    outer_reduce<<<512, 256, 0, stream>>>(bufA, h64, N);
    final_kernel<<<1, 256, 0, stream>>>(h64, Wl, bl, out);
}